// Round 2
// baseline (187.129 us; speedup 1.0000x reference)
//
#include <hip/hip_runtime.h>

#define MDIM 512
#define LDIM 31
#define WDIM 542            // MDIM + LDIM - 1
#define ROW_IN (MDIM*LDIM)  // 15872 floats per (b,r) row
#define NROWS 2048          // B * MDIM
#define BLK_C 256           // c-values per chunk
#define NCH 3               // ceil(542/256)
#define SROWS (BLK_C + 32)  // staged rows m in [c0-31, c0+256] -> 288
#define SFLT (SROWS*LDIM + 4) // 8932 floats (3-float front pad for alignment)

__device__ __forceinline__ float wave_max(float v) {
    #pragma unroll
    for (int off = 32; off > 0; off >>= 1)
        v = fmaxf(v, __shfl_xor(v, off));
    return v;
}

__device__ __forceinline__ float sigmoid10(float h) {
    return 1.0f / (1.0f + __expf(-10.0f * h));
}

__global__ void kInit(unsigned int* g) {
    if (threadIdx.x < 2) g[threadIdx.x] = 0u;
}

// grid (NCH, NROWS). Each block: chunk of 256 c-values of one (b,r) row.
// Computes y_raw chunk -> global, and partial y-max / Z-max -> atomics.
__global__ __launch_bounds__(256) void kMain(const float* __restrict__ inp,
                                             const float* __restrict__ H,
                                             float* __restrict__ y_out,
                                             unsigned int* __restrict__ gmax) {
    __shared__ __align__(16) float s_flat[SFLT];   // 35728 B
    __shared__ float s_hs[SROWS];                  // 1152 B
    __shared__ float s_y[BLK_C + 2];               // y[c0-1 .. c0+256]
    __shared__ float s_red[8];

    const int chunk = blockIdx.x;
    const int br    = blockIdx.y;
    const int r     = br & (MDIM - 1);
    const int tid   = threadIdx.x;
    const int c0    = chunk * BLK_C;

    const float* in_row = inp + (size_t)br * ROW_IN;
    const int gstart = (c0 - 31) * LDIM;  // float offset of row m=c0-31; === 3 (mod 4)
    const int gs4    = gstart - 3;        // 16B-aligned window start

    // ---- stage input window (zero halo outside [0, ROW_IN)) ----
    for (int t = tid; t < SFLT / 4; t += 256) {
        const int fg = gs4 + 4 * t;
        float4 v;
        if (fg >= 0 && fg + 4 <= ROW_IN) {
            v = *(const float4*)(in_row + fg);
        } else {
            float tmp[4];
            #pragma unroll
            for (int j = 0; j < 4; ++j) {
                const int g = fg + j;
                tmp[j] = (g >= 0 && g < ROW_IN) ? in_row[g] : 0.f;
            }
            v = make_float4(tmp[0], tmp[1], tmp[2], tmp[3]);
        }
        *(float4*)(s_flat + 4 * t) = v;
    }
    // ---- stage Hs window (zero outside [0, MDIM)) ----
    const float* hrow = H + (size_t)r * MDIM;
    for (int t = tid; t < SROWS; t += 256) {
        const int m = c0 - 31 + t;
        s_hs[t] = (m >= 0 && m < MDIM) ? sigmoid10(hrow[m]) : 0.f;
    }
    __syncthreads();

    // ---- y[c] for c in [c0-1, c0+256]; fully unrolled 31-tap diagonal ----
    // y[c] = sum_k Hs[c-30+k] * (0.25*x[m][i-1] + 0.5*x[m][i] + 0.25*x[m][i+1]),
    //        m = c-30+k, i = 30-k (compile-time per unrolled k; halo is zero)
    float lmaxy = 0.f;
    for (int lc = tid; lc < BLK_C + 2; lc += 256) {
        const int cc = c0 - 1 + lc;
        float acc = 0.f;
        #pragma unroll
        for (int k = 0; k <= 30; ++k) {
            const int i = 30 - k;
            const float* p = s_flat + 3 + (lc + k) * LDIM;
            float v = 0.5f * p[i];
            if (k < 30) v += 0.25f * p[i - 1];   // i>0 term (compile-time)
            if (k > 0)  v += 0.25f * p[i + 1];   // i<30 term (compile-time)
            acc = fmaf(s_hs[lc + k], v, acc);
        }
        s_y[lc] = acc;
        if (lc >= 1 && lc <= BLK_C && cc < WDIM) {
            y_out[(size_t)br * WDIM + cc] = acc;
            lmaxy = fmaxf(lmaxy, acc);
        }
    }
    __syncthreads();

    // ---- Z-max: for e = m+l in chunk, max over l of Hs[e-l]*blur_l(y)[e] ----
    float lmaxz = 0.f;
    {
        const int e = c0 + tid;
        if (e < WDIM) {
            const float yl = s_y[tid], ym = s_y[tid + 1], yr = s_y[tid + 2];
            const float wf  = 0.25f * yl + 0.5f * ym + 0.25f * yr; // l in [1,29]
            const float w0  = 0.5f * ym + 0.25f * yr;              // l = 0
            const float w30 = 0.25f * yl + 0.5f * ym;              // l = 30
            float hm = s_hs[tid + 2];                  // l=29 -> lm = tid+2
            #pragma unroll
            for (int j = 3; j <= 30; ++j) hm = fmaxf(hm, s_hs[tid + j]);
            lmaxz = fmaxf(wf * hm,
                          fmaxf(w0 * s_hs[tid + 31], w30 * s_hs[tid + 1]));
        }
    }

    const float wy = wave_max(lmaxy);
    const float wz = wave_max(lmaxz);
    const int wave = tid >> 6, lane = tid & 63;
    if (lane == 0) { s_red[wave] = wy; s_red[4 + wave] = wz; }
    __syncthreads();
    if (tid == 0) {
        float my = fmaxf(fmaxf(s_red[0], s_red[1]), fmaxf(s_red[2], s_red[3]));
        float mz = fmaxf(fmaxf(s_red[4], s_red[5]), fmaxf(s_red[6], s_red[7]));
        atomicMax(&gmax[0], __float_as_uint(my));
        atomicMax(&gmax[1], __float_as_uint(mz));
    }
}

// One block per (b, r) row. Writes Xout (normalized Z), normalizes its own
// y row in place, and (b==0) writes Hs.
__global__ __launch_bounds__(256) void kB(const float* __restrict__ H,
                                          float* __restrict__ out,
                                          const unsigned int* __restrict__ gmax) {
    __shared__ float s_y[WDIM];
    __shared__ float s_hs[MDIM];

    const int br  = blockIdx.x;
    const int b   = br >> 9;
    const int r   = br & (MDIM - 1);
    const int tid = threadIdx.x;

    float* xout  = out;                                   // [NROWS][ROW_IN]
    float* yout  = out + (size_t)NROWS * ROW_IN;          // [NROWS][WDIM]
    float* hsout = yout + (size_t)NROWS * WDIM;           // [MDIM*MDIM]

    for (int t = tid; t < WDIM; t += 256) s_y[t] = yout[(size_t)br * WDIM + t];
    const float* hrow = H + (size_t)r * MDIM;
    for (int t = tid; t < MDIM; t += 256) s_hs[t] = sigmoid10(hrow[t]);
    __syncthreads();

    const float inv_my = 1.0f / __uint_as_float(gmax[0]);
    const float inv_mz = 1.0f / __uint_as_float(gmax[1]);

    float4* xr4 = (float4*)(xout + (size_t)br * ROW_IN);
    for (int t4 = tid; t4 < ROW_IN / 4; t4 += 256) {
        const int e = t4 * 4;
        float vals[4];
        #pragma unroll
        for (int j = 0; j < 4; ++j) {
            const int idx = e + j;
            const int m = idx / LDIM;
            const int l = idx - m * LDIM;
            float v = 0.5f * s_y[m + l];
            if (l > 0)        v += 0.25f * s_y[m + l - 1];
            if (l < LDIM - 1) v += 0.25f * s_y[m + l + 1];
            vals[j] = v * s_hs[m] * inv_mz;
        }
        float4 o; o.x = vals[0]; o.y = vals[1]; o.z = vals[2]; o.w = vals[3];
        xr4[t4] = o;
    }

    for (int t = tid; t < WDIM; t += 256)
        yout[(size_t)br * WDIM + t] = s_y[t] * inv_my;

    if (b == 0)
        for (int t = tid; t < MDIM; t += 256)
            hsout[(size_t)r * MDIM + t] = s_hs[t];
}

extern "C" void kernel_launch(void* const* d_in, const int* in_sizes, int n_in,
                              void* d_out, int out_size, void* d_ws, size_t ws_size,
                              hipStream_t stream) {
    const float* inp = (const float*)d_in[0];   // (4,512,512,31) f32
    const float* H   = (const float*)d_in[1];   // (1,512,512,1,1) f32
    float* out = (float*)d_out;
    unsigned int* gmax = (unsigned int*)d_ws;
    float* yraw = out + (size_t)NROWS * ROW_IN; // y slot: raw from kMain, normalized by kB

    hipLaunchKernelGGL(kInit, dim3(1), dim3(64), 0, stream, gmax);
    hipLaunchKernelGGL(kMain, dim3(NCH, NROWS), dim3(256), 0, stream, inp, H, yraw, gmax);
    hipLaunchKernelGGL(kB, dim3(NROWS), dim3(256), 0, stream, H, out, gmax);
}

// Round 3
// 73.844 us; speedup vs baseline: 2.5341x; 2.5341x over previous
//
#include <hip/hip_runtime.h>

#define MDIM 512
#define LDIM 31
#define WDIM 542            // MDIM + LDIM - 1
#define ROW_IN (MDIM*LDIM)  // 15872 floats per (b,r) row
#define NROWS 2048          // B * MDIM
#define BLK_C 256
#define NCH 3
#define NR 290              // staged rows m in [c0-32, c0+257]
#define SX 8990             // NR*LDIM
#define SX4 2248            // ceil(SX/4)
#define NSLOT 8

__device__ __forceinline__ float wave_max(float v) {
    #pragma unroll
    for (int off = 32; off > 0; off >>= 1)
        v = fmaxf(v, __shfl_xor(v, off));
    return v;
}

__device__ __forceinline__ float sigmoid10(float h) {
    return 1.0f / (1.0f + __expf(-10.0f * h));
}

__global__ void kInit(unsigned int* g) {
    const int t = threadIdx.x;
    for (int i = t; i < NSLOT * 32 + 2; i += 256) g[i] = 0u;
}

// g[c] = sum_i Hs[c-i]*x[c-i][i], i=0..30. s_hs/s_x are zero outside valid m.
__device__ __forceinline__ float compute_g(int c, int rlo,
                                           const float* __restrict__ s_hs,
                                           const float* __restrict__ s_x) {
    const float* hb = s_hs + (c - rlo);            // hb[-i]   = Hs[c-i]
    const float* xb = s_x + (c - rlo) * LDIM;      // xb[-30i] = x[c-i][i]
    float a0 = 0.f, a1 = 0.f, a2 = 0.f, a3 = 0.f;
    #pragma unroll
    for (int i = 0; i < 28; i += 4) {
        a0 = fmaf(hb[-i],     xb[-30 * i],       a0);
        a1 = fmaf(hb[-i - 1], xb[-30 * (i + 1)], a1);
        a2 = fmaf(hb[-i - 2], xb[-30 * (i + 2)], a2);
        a3 = fmaf(hb[-i - 3], xb[-30 * (i + 3)], a3);
    }
    a0 = fmaf(hb[-28], xb[-840], a0);
    a1 = fmaf(hb[-29], xb[-870], a1);
    a2 = fmaf(hb[-30], xb[-900], a2);
    return (a0 + a1) + (a2 + a3);
}

__device__ __forceinline__ float yval(int ys, int c, int rlo,
                                      const float* __restrict__ s_hs,
                                      const float* __restrict__ s_x,
                                      const float* __restrict__ s_g) {
    const int rb = c - 31 - rlo;   // >= 0 for all tasks
    const int rc = c + 1 - rlo;    // <= NR-1 for all tasks
    const float B = s_hs[rb] * s_x[rb * LDIM + 30];
    const float C = s_hs[rc] * s_x[rc * LDIM];
    return 0.5f * s_g[ys + 1] + 0.25f * (s_g[ys] - B) + 0.25f * (s_g[ys + 2] - C);
}

__global__ __launch_bounds__(256, 4) void kMain(const float* __restrict__ inp,
                                                const float* __restrict__ H,
                                                float* __restrict__ y_out,
                                                unsigned int* __restrict__ slots) {
    __shared__ __align__(16) float s_x[SX4 * 4];   // 35968 B
    __shared__ float s_hs[NR];
    __shared__ float s_g[BLK_C + 4];
    __shared__ float s_y[BLK_C + 2];
    __shared__ float s_red[8];

    const int chunk = blockIdx.x;
    const int br    = blockIdx.y;
    const int r     = br & (MDIM - 1);
    const int t     = threadIdx.x;
    const int c0    = chunk * BLK_C;
    const int rlo   = c0 - 32;

    // ---- stage x window: 9 unrolled clamped float4 loads, all in flight ----
    {
        const float4* row4 = (const float4*)(inp + (size_t)br * ROW_IN);
        const int g4start = (rlo * LDIM) >> 2;     // rlo*31 is divisible by 4
        float4 v[9];
        int ok[9];
        #pragma unroll
        for (int j = 0; j < 9; ++j) {
            const int idx = t + 256 * j;
            const int qq  = g4start + idx;
            const int qc  = qq < 0 ? 0 : (qq > ROW_IN / 4 - 1 ? ROW_IN / 4 - 1 : qq);
            ok[j] = (qq == qc);
            v[j]  = row4[qc];
        }
        #pragma unroll
        for (int j = 0; j < 9; ++j) {
            const int idx = t + 256 * j;
            float4 vv = v[j];
            if (!ok[j]) vv = make_float4(0.f, 0.f, 0.f, 0.f);
            if (idx < SX4) ((float4*)s_x)[idx] = vv;
        }
    }
    // ---- stage Hs window (zero outside [0, MDIM)) ----
    {
        const float* hrow = H + (size_t)r * MDIM;
        #pragma unroll
        for (int j = 0; j < 2; ++j) {
            const int idx = t + 256 * j;
            if (idx < NR) {
                const int m = rlo + idx;
                s_hs[idx] = (m >= 0 && m < MDIM) ? sigmoid10(hrow[m]) : 0.f;
            }
        }
    }
    __syncthreads();

    // ---- g phase: s_g[gt] <-> c = c0 - 2 + gt, gt in [0, 260) ----
    s_g[t + 2] = compute_g(c0 + t, rlo, s_hs, s_x);
    if (t < 2)         s_g[t]     = compute_g(c0 - 2 + t, rlo, s_hs, s_x);
    else if (t >= 254) s_g[t + 4] = compute_g(c0 + t + 2, rlo, s_hs, s_x);
    __syncthreads();

    // ---- y phase: s_y[ys] <-> c = c0 - 1 + ys, ys in [0, 258) ----
    float lmaxy = 0.f;
    {
        const int c = c0 + t;
        const float yv = yval(t + 1, c, rlo, s_hs, s_x, s_g);
        s_y[t + 1] = yv;
        if (c < WDIM) {
            y_out[(size_t)br * WDIM + c] = yv;
            lmaxy = yv;
        }
        if (t == 0)   s_y[0]   = yval(0,   c0 - 1,   rlo, s_hs, s_x, s_g);
        if (t == 255) s_y[257] = yval(257, c0 + 256, rlo, s_hs, s_x, s_g);
    }
    __syncthreads();

    // ---- Z-max phase: e = c0 + t ----
    float lmaxz = 0.f;
    if (c0 + t < WDIM) {
        const float yl = s_y[t], ym = s_y[t + 1], yr = s_y[t + 2];
        const float wf  = 0.25f * yl + 0.5f * ym + 0.25f * yr;  // l in [1,29]
        const float w0  = 0.5f * ym + 0.25f * yr;               // l = 0
        const float w30 = 0.25f * yl + 0.5f * ym;               // l = 30
        float hm = s_hs[t + 3];                                 // l=29
        #pragma unroll
        for (int j = 4; j <= 31; ++j) hm = fmaxf(hm, s_hs[t + j]);
        lmaxz = fmaxf(wf * hm, fmaxf(w0 * s_hs[t + 32], w30 * s_hs[t + 2]));
    }

    // ---- block reduce + hashed-slot atomics ----
    const float wy = wave_max(lmaxy);
    const float wz = wave_max(lmaxz);
    const int wv = t >> 6, ln = t & 63;
    if (ln == 0) { s_red[wv] = wy; s_red[4 + wv] = wz; }
    __syncthreads();
    if (t == 0) {
        const float my = fmaxf(fmaxf(s_red[0], s_red[1]), fmaxf(s_red[2], s_red[3]));
        const float mz = fmaxf(fmaxf(s_red[4], s_red[5]), fmaxf(s_red[6], s_red[7]));
        const int slot = br & (NSLOT - 1);
        atomicMax(&slots[slot * 32],      __float_as_uint(my));
        atomicMax(&slots[slot * 32 + 16], __float_as_uint(mz));
    }
}

__global__ void kRed(unsigned int* slots) {
    const int t = threadIdx.x;  // 64
    float my = 0.f, mz = 0.f;
    if (t < NSLOT) {
        my = __uint_as_float(slots[t * 32]);
        mz = __uint_as_float(slots[t * 32 + 16]);
    }
    my = wave_max(my);
    mz = wave_max(mz);
    if (t == 0) {
        slots[NSLOT * 32]     = __float_as_uint(my);
        slots[NSLOT * 32 + 1] = __float_as_uint(mz);
    }
}

// One block per (b, r) row. Writes Xout (normalized Z), normalizes its own
// y row in place, and (b==0) writes Hs.
__global__ __launch_bounds__(256) void kB(const float* __restrict__ H,
                                          float* __restrict__ out,
                                          const unsigned int* __restrict__ slots) {
    __shared__ float s_y[WDIM];
    __shared__ float s_hs[MDIM];

    const int br  = blockIdx.x;
    const int b   = br >> 9;
    const int r   = br & (MDIM - 1);
    const int tid = threadIdx.x;

    float* xout  = out;                                   // [NROWS][ROW_IN]
    float* yout  = out + (size_t)NROWS * ROW_IN;          // [NROWS][WDIM]
    float* hsout = yout + (size_t)NROWS * WDIM;           // [MDIM*MDIM]

    for (int t = tid; t < WDIM; t += 256) s_y[t] = yout[(size_t)br * WDIM + t];
    const float* hrow = H + (size_t)r * MDIM;
    for (int t = tid; t < MDIM; t += 256) s_hs[t] = sigmoid10(hrow[t]);
    __syncthreads();

    const float inv_my = 1.0f / __uint_as_float(slots[NSLOT * 32]);
    const float inv_mz = 1.0f / __uint_as_float(slots[NSLOT * 32 + 1]);

    float4* xr4 = (float4*)(xout + (size_t)br * ROW_IN);
    for (int t4 = tid; t4 < ROW_IN / 4; t4 += 256) {
        const int e = t4 * 4;
        float vals[4];
        #pragma unroll
        for (int j = 0; j < 4; ++j) {
            const int idx = e + j;
            const int m = idx / LDIM;
            const int l = idx - m * LDIM;
            float v = 0.5f * s_y[m + l];
            if (l > 0)        v += 0.25f * s_y[m + l - 1];
            if (l < LDIM - 1) v += 0.25f * s_y[m + l + 1];
            vals[j] = v * s_hs[m] * inv_mz;
        }
        float4 o; o.x = vals[0]; o.y = vals[1]; o.z = vals[2]; o.w = vals[3];
        xr4[t4] = o;
    }

    for (int t = tid; t < WDIM; t += 256)
        yout[(size_t)br * WDIM + t] = s_y[t] * inv_my;

    if (b == 0)
        for (int t = tid; t < MDIM; t += 256)
            hsout[(size_t)r * MDIM + t] = s_hs[t];
}

extern "C" void kernel_launch(void* const* d_in, const int* in_sizes, int n_in,
                              void* d_out, int out_size, void* d_ws, size_t ws_size,
                              hipStream_t stream) {
    const float* inp = (const float*)d_in[0];   // (4,512,512,31) f32
    const float* H   = (const float*)d_in[1];   // (1,512,512,1,1) f32
    float* out = (float*)d_out;
    unsigned int* slots = (unsigned int*)d_ws;  // 8 padded slots + 2 finals
    float* yraw = out + (size_t)NROWS * ROW_IN; // y slot: raw from kMain, normalized by kB

    hipLaunchKernelGGL(kInit, dim3(1), dim3(256), 0, stream, slots);
    hipLaunchKernelGGL(kMain, dim3(NCH, NROWS), dim3(256), 0, stream, inp, H, yraw, slots);
    hipLaunchKernelGGL(kRed, dim3(1), dim3(64), 0, stream, slots);
    hipLaunchKernelGGL(kB, dim3(NROWS), dim3(256), 0, stream, H, out, slots);
}